// Round 13
// baseline (91.929 us; speedup 1.0000x reference)
//
#include <hip/hip_runtime.h>

#define NN 64
#define N3 (64*64*64)
#define DS 32

#define LOG2E 1.4426950408889634f
// sqrt(0.5 * log2(e)) — features pre-scaled so w = exp2(-dot2(d,d))
#define FSCALE 0.8493218002880191f

typedef _Float16 h2  __attribute__((ext_vector_type(2)));
typedef __fp16   h2f __attribute__((ext_vector_type(2)));

__device__ __forceinline__ float fexp2(float x) { return __builtin_amdgcn_exp2f(x); }

__device__ __forceinline__ h2 u2h(unsigned u) { union { unsigned u; h2 h; } c; c.u = u; return c.h; }
__device__ __forceinline__ unsigned h2u(h2 h) { union { unsigned u; h2 h; } c; c.h = h; return c.u; }
__device__ __forceinline__ h2 pkh(float a, float b) {
    union { h2f a; h2 b; } c; c.a = __builtin_amdgcn_cvt_pkrtz(a, b); return c.b;
}
__device__ __forceinline__ float fdot2(h2 a, h2 b) {
    union { h2 h; h2f f; } ca, cb; ca.h = a; cb.h = b;
    return __builtin_amdgcn_fdot2(ca.f, cb.f, 0.0f, false);
}

// ---------------- fused mean-field iteration ----------------
// R12 structure (tile 8^3, 1024 thr, S=4 split, XCD-chunked swizzle, prior
// folded into FIRST) + branch-free register-double-buffered phase loop:
// each wave prefetches phase p+4's LDS window into a second register set
// while computing phase p, eliminating the per-phase lgkmcnt stall.

#define TXD 8
#define TYD 8
#define TZD 8
#define TZR 4
#define RZ 2
#define HX 12
#define HY 12
#define HZ 12
#define PZ 14          // pS padded z stride
#define CPX 6          // coarse pm extent per block
#define CSX 10         // staged coarse extent (pm + halo 2)

template<bool FIRST, bool LAST>
__global__ __launch_bounds__(1024, 8) void k_iter(
    const float* __restrict__ unary,     // planar [4][N3]
    const uint2* __restrict__ pin,       // !FIRST: packed f16x4 softmax
    const unsigned* __restrict__ fpk_in, // !FIRST: packed img features
    const float* __restrict__ img,
    const float* __restrict__ atlas,
    const float* __restrict__ alabel,
    const float* __restrict__ pnorm,
    const float* __restrict__ snorm,
    const float* __restrict__ pweight,
    const int* __restrict__ pstart,
    const float* __restrict__ sweight,
    const float* __restrict__ compat,
    float4* __restrict__ unary4,         // FIRST: write; !FIRST: read
    unsigned* __restrict__ fpk_out,      // FIRST: write
    uint2* __restrict__ pout,            // !LAST: packed softmax out
    float* __restrict__ qout)            // LAST: planar q out
{
    // raw1 is phase-unioned: nbS (prior staging, FIRST only) then pS (main).
    __shared__ __align__(16) unsigned char raw1[16384];
    auto nbS = reinterpret_cast<uint4 (*)[CSX][CSX]>(raw1);   // [10][10][10] {f2pk,l01,l23,f1pk}
    auto pS  = reinterpret_cast<uint2 (*)[HY][PZ]>(raw1);     // [12][12][14] p f16x4
    __shared__ __align__(8)  unsigned fS[HX][HY][PZ];         // features f16x2
    __shared__ __align__(16) uint4    accS[3][TXD*TYD*TZR];   // partial sums
    __shared__ __align__(8)  uint2    pmS[CPX][CPX][CPX];     // prior message f16x4

    const int tzg = threadIdx.x, ty = threadIdx.y;
    const int tx = threadIdx.z & 7, s = threadIdx.z >> 3;     // s wave-uniform

    // XCD-chunked swizzle: dispatch index d -> XCD d%8 (HW round-robin).
    const int bid = blockIdx.x;
    const int w   = ((bid & 7) << 6) | (bid >> 3);
    const int x0b = (w >> 6) * TXD;
    const int y0b = ((w >> 3) & 7) * TYD;
    const int z0b = (w & 7) * TZD;

    const int tid = threadIdx.x + TZR*threadIdx.y + (TZR*TYD)*threadIdx.z;

    const int tz0 = tzg * RZ;
    const int gx = x0b + tx, gy = y0b + ty;
    const int g = (gx*NN + gy)*NN + z0b + tz0;

    float4 u40, u41;
    float sw0, sw1, sw2, sw3;
    float cw[16];

    if (FIRST) {
        const int cxlo = (x0b*31)/63, cylo = (y0b*31)/63, czlo = (z0b*31)/63;
        const float pnf = pnorm[0] * FSCALE;

        // ---- phase 1: stage coarse features/labels (10^3) ----
        if (tid < CSX*CSX*CSX) {
            int lz = tid % CSX; int r = tid / CSX; int ly = r % CSX; int lx = r / CSX;
            int cx = cxlo - 2 + lx, cy = cylo - 2 + ly, cz = czlo - 2 + lz;
            uint4 v = make_uint4(0u, 0u, 0u, 0u);
            if ((unsigned)cx < DS && (unsigned)cy < DS && (unsigned)cz < DS) {
                const float scale = 63.0f / 31.0f;
                float posx = cx*scale; int a0i = (int)posx; float wx = posx - a0i; int a1i = a0i+1 <= 63 ? a0i+1 : 63;
                float posy = cy*scale; int b0i = (int)posy; float wy = posy - b0i; int b1i = b0i+1 <= 63 ? b0i+1 : 63;
                float posz = cz*scale; int d0i = (int)posz; float wz = posz - d0i; int d1i = d0i+1 <= 63 ? d0i+1 : 63;
                float w000=(1-wx)*(1-wy)*(1-wz), w001=(1-wx)*(1-wy)*wz;
                float w010=(1-wx)*wy*(1-wz),     w011=(1-wx)*wy*wz;
                float w100=wx*(1-wy)*(1-wz),     w101=wx*(1-wy)*wz;
                float w110=wx*wy*(1-wz),         w111=wx*wy*wz;
                int c000=(a0i*NN+b0i)*NN+d0i, c001=(a0i*NN+b0i)*NN+d1i;
                int c010=(a0i*NN+b1i)*NN+d0i, c011=(a0i*NN+b1i)*NN+d1i;
                int c100=(a1i*NN+b0i)*NN+d0i, c101=(a1i*NN+b0i)*NN+d1i;
                int c110=(a1i*NN+b1i)*NN+d0i, c111=(a1i*NN+b1i)*NN+d1i;
                auto tri = [&](const float* p) -> float {
                    return p[c000]*w000 + p[c001]*w001 + p[c010]*w010 + p[c011]*w011
                         + p[c100]*w100 + p[c101]*w101 + p[c110]*w110 + p[c111]*w111;
                };
                const float4* lab = (const float4*)alabel;
                float4 l = make_float4(0.f,0.f,0.f,0.f);
                {
                    float4 t;
                    t = lab[c000]; l.x += w000*t.x; l.y += w000*t.y; l.z += w000*t.z; l.w += w000*t.w;
                    t = lab[c001]; l.x += w001*t.x; l.y += w001*t.y; l.z += w001*t.z; l.w += w001*t.w;
                    t = lab[c010]; l.x += w010*t.x; l.y += w010*t.y; l.z += w010*t.z; l.w += w010*t.w;
                    t = lab[c011]; l.x += w011*t.x; l.y += w011*t.y; l.z += w011*t.z; l.w += w011*t.w;
                    t = lab[c100]; l.x += w100*t.x; l.y += w100*t.y; l.z += w100*t.z; l.w += w100*t.w;
                    t = lab[c101]; l.x += w101*t.x; l.y += w101*t.y; l.z += w101*t.z; l.w += w101*t.w;
                    t = lab[c110]; l.x += w110*t.x; l.y += w110*t.y; l.z += w110*t.z; l.w += w110*t.w;
                    t = lab[c111]; l.x += w111*t.x; l.y += w111*t.y; l.z += w111*t.z; l.w += w111*t.w;
                }
                v = make_uint4(h2u(pkh(pnf*tri(atlas), pnf*tri(atlas + N3))),
                               h2u(pkh(l.x, l.y)), h2u(pkh(l.z, l.w)),
                               h2u(pkh(pnf*tri(img), pnf*tri(img + N3))));
            }
            nbS[lx][ly][lz] = v;
        }
        __syncthreads();

        // ---- phase 2: prior message on the 6^3 coarse points ----
        if (tid < CPX*CPX*CPX) {
            int pz = tid % CPX; int r = tid / CPX; int py = r % CPX; int px = r / CPX;
            int cx = cxlo + px, cy = cylo + py, cz = czlo + pz;
            uint2 o = make_uint2(0u, 0u);
            if (cx < DS && cy < DS && cz < DS) {
                h2 ncf = -u2h(nbS[px+2][py+2][pz+2].w);
                float a0=0.f, a1=0.f, a2=0.f, a3=0.f;
                for (int dx = -2; dx <= 2; ++dx) {
                    int xx = cx + dx; if ((unsigned)xx >= DS) continue;
                    for (int dy = -2; dy <= 2; ++dy) {
                        int yy = cy + dy; if ((unsigned)yy >= DS) continue;
                        #pragma unroll
                        for (int dz = -2; dz <= 2; ++dz) {
                            int zz = cz + dz; if ((unsigned)zz >= DS) continue;
                            uint4 v = nbS[px+2+dx][py+2+dy][pz+2+dz];
                            h2 d = u2h(v.x) + ncf;
                            float ww = fexp2(-fdot2(d, d));
                            h2 l01 = u2h(v.y), l23 = u2h(v.z);
                            a0 += ww*(float)l01.x; a1 += ww*(float)l01.y;
                            a2 += ww*(float)l23.x; a3 += ww*(float)l23.y;
                        }
                    }
                }
                o = make_uint2(h2u(pkh(a0, a1)), h2u(pkh(a2, a3)));
            }
            pmS[px][py][pz] = o;
        }
        __syncthreads();

        // ---- phase 3: s==0 threads upsample + fold their own 2 voxels ----
        if (s == 0) {
            sw0 = sweight[0]; sw1 = sweight[1]; sw2 = sweight[2]; sw3 = sweight[3];
            #pragma unroll
            for (int k = 0; k < 16; ++k) cw[k] = compat[k];

            const float S13 = 31.0f / 63.0f;
            float posx = gx*S13; int xc0 = (int)posx; float wxf = posx - xc0; int xc1 = xc0 < 31 ? xc0+1 : 31;
            float posy = gy*S13; int yc0 = (int)posy; float wyf = posy - yc0; int yc1 = yc0 < 31 ? yc0+1 : 31;
            int lx0 = xc0-cxlo, lx1 = xc1-cxlo;
            int ly0 = yc0-cylo, ly1 = yc1-cylo;
            const int ps0 = pstart[0], ps1 = pstart[1], ps2 = pstart[2];

            auto up = [&](uint2 u) -> float4 {
                h2 a = u2h(u.x), b = u2h(u.y);
                return make_float4((float)a.x, (float)a.y, (float)b.x, (float)b.y);
            };

            #pragma unroll
            for (int rz = 0; rz < RZ; ++rz) {
                int gz = z0b + tz0 + rz;
                float posz = gz*S13; int zc0 = (int)posz; float wzf = posz - zc0; int zc1 = zc0 < 31 ? zc0+1 : 31;
                int lz0 = zc0-czlo, lz1 = zc1-czlo;
                float4 p000 = up(pmS[lx0][ly0][lz0]), p001 = up(pmS[lx0][ly0][lz1]);
                float4 p010 = up(pmS[lx0][ly1][lz0]), p011 = up(pmS[lx0][ly1][lz1]);
                float4 p100 = up(pmS[lx1][ly0][lz0]), p101 = up(pmS[lx1][ly0][lz1]);
                float4 p110 = up(pmS[lx1][ly1][lz0]), p111 = up(pmS[lx1][ly1][lz1]);
                float w000=(1-wxf)*(1-wyf)*(1-wzf), w001=(1-wxf)*(1-wyf)*wzf;
                float w010=(1-wxf)*wyf*(1-wzf),     w011=(1-wxf)*wyf*wzf;
                float w100=wxf*(1-wyf)*(1-wzf),     w101=wxf*(1-wyf)*wzf;
                float w110=wxf*wyf*(1-wzf),         w111=wxf*wyf*wzf;
                float pw = pweight[(ps0+gx)*96*96 + (ps1+gy)*96 + (ps2+gz)];
                float pr0 = pw*(w000*p000.x + w001*p001.x + w010*p010.x + w011*p011.x + w100*p100.x + w101*p101.x + w110*p110.x + w111*p111.x);
                float pr1 = pw*(w000*p000.y + w001*p001.y + w010*p010.y + w011*p011.y + w100*p100.y + w101*p101.y + w110*p110.y + w111*p111.y);
                float pr2 = pw*(w000*p000.z + w001*p001.z + w010*p010.z + w011*p011.z + w100*p100.z + w101*p101.z + w110*p110.z + w111*p111.z);
                float pr3 = pw*(w000*p000.w + w001*p001.w + w010*p010.w + w011*p011.w + w100*p100.w + w101*p101.w + w110*p110.w + w111*p111.w);

                int gg = g + rz;
                float4 q;
                q.x = unary[gg]      + cw[0]*pr0  + cw[1]*pr1  + cw[2]*pr2  + cw[3]*pr3;
                q.y = unary[gg+N3]   + cw[4]*pr0  + cw[5]*pr1  + cw[6]*pr2  + cw[7]*pr3;
                q.z = unary[gg+2*N3] + cw[8]*pr0  + cw[9]*pr1  + cw[10]*pr2 + cw[11]*pr3;
                q.w = unary[gg+3*N3] + cw[12]*pr0 + cw[13]*pr1 + cw[14]*pr2 + cw[15]*pr3;
                unary4[gg] = q;          // for iterations 2-4
                if (rz == 0) u40 = q; else u41 = q;
            }
        }
        __syncthreads();   // nbS/pmS dead; raw1 reusable as pS
    }

    // ---- halo load: 12^3 = 1728 voxels, 2 rounds of 1024 ----
    const float sc = FIRST ? snorm[0] * FSCALE : 0.0f;
    #pragma unroll
    for (int rr = 0; rr < 2; ++rr) {
        int i = tid + rr*1024;
        if (i < HX*HY*HZ) {
            int lz = i % HZ; int r = i / HZ;
            int ly = r % HY; int lx = r / HY;
            int hgx = x0b + lx - 2, hgy = y0b + ly - 2, hgz = z0b + lz - 2;
            uint2 pu = make_uint2(0u, 0u);
            unsigned fu = 0u;
            if ((unsigned)hgx < NN && (unsigned)hgy < NN && (unsigned)hgz < NN) {
                int hg = (hgx*NN + hgy)*NN + hgz;
                if (FIRST) {
                    float q0 = unary[hg], q1 = unary[hg+N3], q2 = unary[hg+2*N3], q3 = unary[hg+3*N3];
                    float m = fmaxf(fmaxf(q0,q1), fmaxf(q2,q3));
                    float e0 = fexp2((q0-m)*LOG2E);
                    float e1 = fexp2((q1-m)*LOG2E);
                    float e2 = fexp2((q2-m)*LOG2E);
                    float e3 = fexp2((q3-m)*LOG2E);
                    float inv = 1.0f/(e0+e1+e2+e3);
                    pu = make_uint2(h2u(pkh(e0*inv, e1*inv)), h2u(pkh(e2*inv, e3*inv)));
                    fu = h2u(pkh(img[hg]*sc, img[hg+N3]*sc));
                    if ((unsigned)(lx-2) < 8u && (unsigned)(ly-2) < 8u && (unsigned)(lz-2) < 8u)
                        fpk_out[hg] = fu;   // features for iterations 2-4
                } else {
                    pu = pin[hg];
                    fu = fpk_in[hg];
                }
            }
            pS[lx][ly][lz] = pu;
            fS[lx][ly][lz] = fu;
        }
    }

    // hoisted epilogue operands (s==0 only; FIRST already has them)
    if (!FIRST && s == 0) {
        u40 = unary4[g]; u41 = unary4[g+1];
        sw0 = sweight[0]; sw1 = sweight[1]; sw2 = sweight[2]; sw3 = sweight[3];
        #pragma unroll
        for (int k = 0; k < 16; ++k) cw[k] = compat[k];
    }

    __syncthreads();

    // negated center features (from LDS so the d=0 term is exactly w=1)
    const h2 ncf0 = -u2h(fS[tx+2][ty+2][tz0+2]);
    const h2 ncf1 = -u2h(fS[tx+2][ty+2][tz0+3]);

    h2 a01_0 = (h2)0, a23_0 = (h2)0, a01_1 = (h2)0, a23_1 = (h2)0;

    auto doPhase = [&](uint4 qa_, uint4 qb_, uint4 qc_, uint2 fa_, uint2 fb_, uint2 fc_) {
        unsigned fz[6]  = { fa_.x, fa_.y, fb_.x, fb_.y, fc_.x, fc_.y };
        unsigned p01[6] = { qa_.x, qa_.z, qb_.x, qb_.z, qc_.x, qc_.z };
        unsigned p23[6] = { qa_.y, qa_.w, qb_.y, qb_.w, qc_.y, qc_.w };
        #pragma unroll
        for (int dz = 0; dz < 5; ++dz) {
            {
                h2 d = u2h(fz[dz]) + ncf0;
                float ww = fexp2(-fdot2(d, d));
                h2 w2 = pkh(ww, ww);
                a01_0 = w2 * u2h(p01[dz]) + a01_0;
                a23_0 = w2 * u2h(p23[dz]) + a23_0;
            }
            {
                h2 d = u2h(fz[dz+1]) + ncf1;
                float ww = fexp2(-fdot2(d, d));
                h2 w2 = pkh(ww, ww);
                a01_1 = w2 * u2h(p01[dz+1]) + a01_1;
                a23_1 = w2 * u2h(p23[dz+1]) + a23_1;
            }
        }
    };

    // phase schedule: s=0..2 -> 6 phases (3-s)+4*pp; s=3 -> those + phase 24.
    // Branch-free main loop with register double-buffering: prefetch phase
    // p+4 while computing phase p (clamped dummy prefetch on the last lap).
    int p = 3 - s;
    uint4 qa, qb, qc; uint2 fa, fb, fc;
    {
        int dx = p / 5, dy = p - 5*dx;
        const uint4* pv = reinterpret_cast<const uint4*>(&pS[tx+dx][ty+dy][tz0]);
        const uint2* fv = reinterpret_cast<const uint2*>(&fS[tx+dx][ty+dy][tz0]);
        qa = pv[0]; qb = pv[1]; qc = pv[2];
        fa = fv[0]; fb = fv[1]; fc = fv[2];
    }

    #pragma unroll
    for (int pp = 0; pp < 6; ++pp) {
        int pn = p + 4;
        int pcl = (pn <= 24) ? pn : 24;           // clamp: dummy prefetch stays in-bounds
        int dxn = pcl / 5, dyn = pcl - 5*dxn;
        const uint4* pv = reinterpret_cast<const uint4*>(&pS[tx+dxn][ty+dyn][tz0]);
        const uint2* fv = reinterpret_cast<const uint2*>(&fS[tx+dxn][ty+dyn][tz0]);
        uint4 nqa = pv[0], nqb = pv[1], nqc = pv[2];
        uint2 nfa = fv[0], nfb = fv[1], nfc = fv[2];

        doPhase(qa, qb, qc, fa, fb, fc);

        qa = nqa; qb = nqb; qc = nqc;
        fa = nfa; fb = nfb; fc = nfc;
        p = pn;
    }
    if (s == 3) {
        // after the loop, s==3 holds phase 24 in the prefetch registers
        doPhase(qa, qb, qc, fa, fb, fc);
    }

    const int pid = (tx*TYD + ty)*TZR + tzg;
    if (s != 0) {
        accS[s-1][pid] = make_uint4(h2u(a01_0), h2u(a23_0), h2u(a01_1), h2u(a23_1));
    }
    __syncthreads();

    if (s == 0) {
        #pragma unroll
        for (int j = 0; j < 3; ++j) {
            uint4 v = accS[j][pid];
            a01_0 += u2h(v.x); a23_0 += u2h(v.y);
            a01_1 += u2h(v.z); a23_1 += u2h(v.w);
        }

        float p0, p1, p2, p3;
        float r00, r10, r20, r30, r01, r11, r21, r31;
        p0 = sw0*(float)a01_0.x; p1 = sw1*(float)a01_0.y;
        p2 = sw2*(float)a23_0.x; p3 = sw3*(float)a23_0.y;
        r00 = u40.x + cw[0]*p0  + cw[1]*p1  + cw[2]*p2  + cw[3]*p3;
        r10 = u40.y + cw[4]*p0  + cw[5]*p1  + cw[6]*p2  + cw[7]*p3;
        r20 = u40.z + cw[8]*p0  + cw[9]*p1  + cw[10]*p2 + cw[11]*p3;
        r30 = u40.w + cw[12]*p0 + cw[13]*p1 + cw[14]*p2 + cw[15]*p3;
        p0 = sw0*(float)a01_1.x; p1 = sw1*(float)a01_1.y;
        p2 = sw2*(float)a23_1.x; p3 = sw3*(float)a23_1.y;
        r01 = u41.x + cw[0]*p0  + cw[1]*p1  + cw[2]*p2  + cw[3]*p3;
        r11 = u41.y + cw[4]*p0  + cw[5]*p1  + cw[6]*p2  + cw[7]*p3;
        r21 = u41.z + cw[8]*p0  + cw[9]*p1  + cw[10]*p2 + cw[11]*p3;
        r31 = u41.w + cw[12]*p0 + cw[13]*p1 + cw[14]*p2 + cw[15]*p3;

        if (LAST) {
            *(float2*)(qout + 0*N3 + g) = make_float2(r00, r01);
            *(float2*)(qout + 1*N3 + g) = make_float2(r10, r11);
            *(float2*)(qout + 2*N3 + g) = make_float2(r20, r21);
            *(float2*)(qout + 3*N3 + g) = make_float2(r30, r31);
        } else {
            // softmax + pack (producer side of next iteration)
            float m0 = fmaxf(fmaxf(r00,r10), fmaxf(r20,r30));
            float e00 = fexp2((r00-m0)*LOG2E), e10 = fexp2((r10-m0)*LOG2E);
            float e20 = fexp2((r20-m0)*LOG2E), e30 = fexp2((r30-m0)*LOG2E);
            float i0 = 1.0f/(e00+e10+e20+e30);
            float m1 = fmaxf(fmaxf(r01,r11), fmaxf(r21,r31));
            float e01 = fexp2((r01-m1)*LOG2E), e11 = fexp2((r11-m1)*LOG2E);
            float e21 = fexp2((r21-m1)*LOG2E), e31 = fexp2((r31-m1)*LOG2E);
            float i1 = 1.0f/(e01+e11+e21+e31);
            uint4 o = make_uint4(h2u(pkh(e00*i0, e10*i0)), h2u(pkh(e20*i0, e30*i0)),
                                 h2u(pkh(e01*i1, e11*i1)), h2u(pkh(e21*i1, e31*i1)));
            *reinterpret_cast<uint4*>(&pout[g]) = o;   // g even -> 16B aligned
        }
    }
}

// ---------------- launcher ----------------

extern "C" void kernel_launch(void* const* d_in, const int* in_sizes, int n_in,
                              void* d_out, int out_size, void* d_ws, size_t ws_size,
                              hipStream_t stream)
{
    const float* unary   = (const float*)d_in[0];
    const float* img     = (const float*)d_in[1];
    const float* atlas   = (const float*)d_in[2];
    const float* alabel  = (const float*)d_in[3];
    const int*   pstart  = (const int*)d_in[4];
    const float* snorm   = (const float*)d_in[5];
    const float* sweight = (const float*)d_in[6];
    const float* pnorm   = (const float*)d_in[7];
    const float* pweight = (const float*)d_in[8];
    const float* compat  = (const float*)d_in[9];
    float* out = (float*)d_out;
    float* ws  = (float*)d_ws;

    float4*   unary4 = (float4*)ws;               // N3 float4 (4 MB)
    uint2*    pA     = (uint2*)(ws + 4*N3);       // N3 uint2  (2 MB)
    uint2*    pB     = (uint2*)(ws + 6*N3);       // N3 uint2  (2 MB)
    unsigned* fpk    = (unsigned*)(ws + 8*N3);    // N3 uint   (1 MB)

    dim3 grid(512), block(TZR, TYD, 32);
    k_iter<true, false><<<grid, block, 0, stream>>>(unary, pA, fpk, img, atlas, alabel,
        pnorm, snorm, pweight, pstart, sweight, compat, unary4, fpk, pA, out);
    k_iter<false,false><<<grid, block, 0, stream>>>(unary, pA, fpk, img, atlas, alabel,
        pnorm, snorm, pweight, pstart, sweight, compat, unary4, fpk, pB, out);
    k_iter<false,false><<<grid, block, 0, stream>>>(unary, pB, fpk, img, atlas, alabel,
        pnorm, snorm, pweight, pstart, sweight, compat, unary4, fpk, pA, out);
    k_iter<false,true ><<<grid, block, 0, stream>>>(unary, pA, fpk, img, atlas, alabel,
        pnorm, snorm, pweight, pstart, sweight, compat, unary4, fpk, pB, out);
}

// Round 14
// 90.943 us; speedup vs baseline: 1.0108x; 1.0108x over previous
//
#include <hip/hip_runtime.h>

#define NN 64
#define N3 (64*64*64)
#define DS 32

#define LOG2E 1.4426950408889634f
// sqrt(0.5 * log2(e)) — features pre-scaled so w = exp2(-dot2(d,d))
#define FSCALE 0.8493218002880191f

typedef _Float16 h2  __attribute__((ext_vector_type(2)));
typedef __fp16   h2f __attribute__((ext_vector_type(2)));

__device__ __forceinline__ float fexp2(float x) { return __builtin_amdgcn_exp2f(x); }

__device__ __forceinline__ h2 u2h(unsigned u) { union { unsigned u; h2 h; } c; c.u = u; return c.h; }
__device__ __forceinline__ unsigned h2u(h2 h) { union { unsigned u; h2 h; } c; c.h = h; return c.u; }
__device__ __forceinline__ h2 pkh(float a, float b) {
    union { h2f a; h2 b; } c; c.a = __builtin_amdgcn_cvt_pkrtz(a, b); return c.b;
}
__device__ __forceinline__ float fdot2(h2 a, h2 b) {
    union { h2 h; h2f f; } ca, cb; ca.h = a; cb.h = b;
    return __builtin_amdgcn_fdot2(ca.f, cb.f, 0.0f, false);
}

// ---------------- fused mean-field iteration ----------------
// R12 structure (tile 8^3, XCD-chunked swizzle, prior folded into FIRST,
// producer-packed p) but with 512-thread blocks and S=2 phase split:
// 512 blocks at 4 blocks/CU (vs 2) -> 4 independent barrier domains per CU,
// so one block's main loop covers another block's prologue/drain stalls.
// Total occupancy unchanged: 4 blocks x 8 waves = 32 waves/CU.

#define TXD 8
#define TYD 8
#define TZD 8
#define TZR 4
#define RZ 2
#define HX 12
#define HY 12
#define HZ 12
#define PZ 14          // pS padded z stride
#define CPX 6          // coarse pm extent per block
#define CSX 10         // staged coarse extent (pm + halo 2)

template<bool FIRST, bool LAST>
__global__ __launch_bounds__(512, 8) void k_iter(
    const float* __restrict__ unary,     // planar [4][N3]
    const uint2* __restrict__ pin,       // !FIRST: packed f16x4 softmax
    const unsigned* __restrict__ fpk_in, // !FIRST: packed img features
    const float* __restrict__ img,
    const float* __restrict__ atlas,
    const float* __restrict__ alabel,
    const float* __restrict__ pnorm,
    const float* __restrict__ snorm,
    const float* __restrict__ pweight,
    const int* __restrict__ pstart,
    const float* __restrict__ sweight,
    const float* __restrict__ compat,
    float4* __restrict__ unary4,         // FIRST: write; !FIRST: read
    unsigned* __restrict__ fpk_out,      // FIRST: write
    uint2* __restrict__ pout,            // !LAST: packed softmax out
    float* __restrict__ qout)            // LAST: planar q out
{
    // raw1 is phase-unioned: nbS (prior staging, FIRST only) then pS (main).
    __shared__ __align__(16) unsigned char raw1[16384];
    auto nbS = reinterpret_cast<uint4 (*)[CSX][CSX]>(raw1);   // [10][10][10] {f2pk,l01,l23,f1pk}
    auto pS  = reinterpret_cast<uint2 (*)[HY][PZ]>(raw1);     // [12][12][14] p f16x4
    __shared__ __align__(8)  unsigned fS[HX][HY][PZ];         // features f16x2
    __shared__ __align__(16) uint4    accS[TXD*TYD*TZR];      // partial sums (s==1)
    __shared__ __align__(8)  uint2    pmS[CPX][CPX][CPX];     // prior message f16x4

    const int tzg = threadIdx.x, ty = threadIdx.y;
    const int tx = threadIdx.z & 7, s = threadIdx.z >> 3;     // s wave-uniform (0/1)

    // XCD-chunked swizzle: dispatch index d -> XCD d%8 (HW round-robin).
    const int bid = blockIdx.x;
    const int w   = ((bid & 7) << 6) | (bid >> 3);
    const int x0b = (w >> 6) * TXD;
    const int y0b = ((w >> 3) & 7) * TYD;
    const int z0b = (w & 7) * TZD;

    const int tid = threadIdx.x + TZR*threadIdx.y + (TZR*TYD)*threadIdx.z;  // 0..511

    const int tz0 = tzg * RZ;
    const int gx = x0b + tx, gy = y0b + ty;
    const int g = (gx*NN + gy)*NN + z0b + tz0;

    float4 u40, u41;
    float sw0, sw1, sw2, sw3;
    float cw[16];

    if (FIRST) {
        const int cxlo = (x0b*31)/63, cylo = (y0b*31)/63, czlo = (z0b*31)/63;
        const float pnf = pnorm[0] * FSCALE;

        // ---- phase 1: stage coarse features/labels (10^3), 2 rounds of 512 ----
        #pragma unroll
        for (int r = 0; r < 2; ++r) {
            int i = tid + r*512;
            if (i < CSX*CSX*CSX) {
                int lz = i % CSX; int t = i / CSX; int ly = t % CSX; int lx = t / CSX;
                int cx = cxlo - 2 + lx, cy = cylo - 2 + ly, cz = czlo - 2 + lz;
                uint4 v = make_uint4(0u, 0u, 0u, 0u);
                if ((unsigned)cx < DS && (unsigned)cy < DS && (unsigned)cz < DS) {
                    const float scale = 63.0f / 31.0f;
                    float posx = cx*scale; int a0i = (int)posx; float wx = posx - a0i; int a1i = a0i+1 <= 63 ? a0i+1 : 63;
                    float posy = cy*scale; int b0i = (int)posy; float wy = posy - b0i; int b1i = b0i+1 <= 63 ? b0i+1 : 63;
                    float posz = cz*scale; int d0i = (int)posz; float wz = posz - d0i; int d1i = d0i+1 <= 63 ? d0i+1 : 63;
                    float w000=(1-wx)*(1-wy)*(1-wz), w001=(1-wx)*(1-wy)*wz;
                    float w010=(1-wx)*wy*(1-wz),     w011=(1-wx)*wy*wz;
                    float w100=wx*(1-wy)*(1-wz),     w101=wx*(1-wy)*wz;
                    float w110=wx*wy*(1-wz),         w111=wx*wy*wz;
                    int c000=(a0i*NN+b0i)*NN+d0i, c001=(a0i*NN+b0i)*NN+d1i;
                    int c010=(a0i*NN+b1i)*NN+d0i, c011=(a0i*NN+b1i)*NN+d1i;
                    int c100=(a1i*NN+b0i)*NN+d0i, c101=(a1i*NN+b0i)*NN+d1i;
                    int c110=(a1i*NN+b1i)*NN+d0i, c111=(a1i*NN+b1i)*NN+d1i;
                    auto tri = [&](const float* p) -> float {
                        return p[c000]*w000 + p[c001]*w001 + p[c010]*w010 + p[c011]*w011
                             + p[c100]*w100 + p[c101]*w101 + p[c110]*w110 + p[c111]*w111;
                    };
                    const float4* lab = (const float4*)alabel;
                    float4 l = make_float4(0.f,0.f,0.f,0.f);
                    {
                        float4 t4;
                        t4 = lab[c000]; l.x += w000*t4.x; l.y += w000*t4.y; l.z += w000*t4.z; l.w += w000*t4.w;
                        t4 = lab[c001]; l.x += w001*t4.x; l.y += w001*t4.y; l.z += w001*t4.z; l.w += w001*t4.w;
                        t4 = lab[c010]; l.x += w010*t4.x; l.y += w010*t4.y; l.z += w010*t4.z; l.w += w010*t4.w;
                        t4 = lab[c011]; l.x += w011*t4.x; l.y += w011*t4.y; l.z += w011*t4.z; l.w += w011*t4.w;
                        t4 = lab[c100]; l.x += w100*t4.x; l.y += w100*t4.y; l.z += w100*t4.z; l.w += w100*t4.w;
                        t4 = lab[c101]; l.x += w101*t4.x; l.y += w101*t4.y; l.z += w101*t4.z; l.w += w101*t4.w;
                        t4 = lab[c110]; l.x += w110*t4.x; l.y += w110*t4.y; l.z += w110*t4.z; l.w += w110*t4.w;
                        t4 = lab[c111]; l.x += w111*t4.x; l.y += w111*t4.y; l.z += w111*t4.z; l.w += w111*t4.w;
                    }
                    v = make_uint4(h2u(pkh(pnf*tri(atlas), pnf*tri(atlas + N3))),
                                   h2u(pkh(l.x, l.y)), h2u(pkh(l.z, l.w)),
                                   h2u(pkh(pnf*tri(img), pnf*tri(img + N3))));
                }
                nbS[lx][ly][lz] = v;
            }
        }
        __syncthreads();

        // ---- phase 2: prior message on the 6^3 coarse points ----
        if (tid < CPX*CPX*CPX) {
            int pz = tid % CPX; int r = tid / CPX; int py = r % CPX; int px = r / CPX;
            int cx = cxlo + px, cy = cylo + py, cz = czlo + pz;
            uint2 o = make_uint2(0u, 0u);
            if (cx < DS && cy < DS && cz < DS) {
                h2 ncf = -u2h(nbS[px+2][py+2][pz+2].w);
                float a0=0.f, a1=0.f, a2=0.f, a3=0.f;
                for (int dx = -2; dx <= 2; ++dx) {
                    int xx = cx + dx; if ((unsigned)xx >= DS) continue;
                    for (int dy = -2; dy <= 2; ++dy) {
                        int yy = cy + dy; if ((unsigned)yy >= DS) continue;
                        #pragma unroll
                        for (int dz = -2; dz <= 2; ++dz) {
                            int zz = cz + dz; if ((unsigned)zz >= DS) continue;
                            uint4 v = nbS[px+2+dx][py+2+dy][pz+2+dz];
                            h2 d = u2h(v.x) + ncf;
                            float ww = fexp2(-fdot2(d, d));
                            h2 l01 = u2h(v.y), l23 = u2h(v.z);
                            a0 += ww*(float)l01.x; a1 += ww*(float)l01.y;
                            a2 += ww*(float)l23.x; a3 += ww*(float)l23.y;
                        }
                    }
                }
                o = make_uint2(h2u(pkh(a0, a1)), h2u(pkh(a2, a3)));
            }
            pmS[px][py][pz] = o;
        }
        __syncthreads();

        // ---- phase 3: s==0 threads upsample + fold their own 2 voxels ----
        if (s == 0) {
            sw0 = sweight[0]; sw1 = sweight[1]; sw2 = sweight[2]; sw3 = sweight[3];
            #pragma unroll
            for (int k = 0; k < 16; ++k) cw[k] = compat[k];

            const float S13 = 31.0f / 63.0f;
            float posx = gx*S13; int xc0 = (int)posx; float wxf = posx - xc0; int xc1 = xc0 < 31 ? xc0+1 : 31;
            float posy = gy*S13; int yc0 = (int)posy; float wyf = posy - yc0; int yc1 = yc0 < 31 ? yc0+1 : 31;
            int lx0 = xc0-cxlo, lx1 = xc1-cxlo;
            int ly0 = yc0-cylo, ly1 = yc1-cylo;
            const int ps0 = pstart[0], ps1 = pstart[1], ps2 = pstart[2];

            auto up = [&](uint2 u) -> float4 {
                h2 a = u2h(u.x), b = u2h(u.y);
                return make_float4((float)a.x, (float)a.y, (float)b.x, (float)b.y);
            };

            #pragma unroll
            for (int rz = 0; rz < RZ; ++rz) {
                int gz = z0b + tz0 + rz;
                float posz = gz*S13; int zc0 = (int)posz; float wzf = posz - zc0; int zc1 = zc0 < 31 ? zc0+1 : 31;
                int lz0 = zc0-czlo, lz1 = zc1-czlo;
                float4 p000 = up(pmS[lx0][ly0][lz0]), p001 = up(pmS[lx0][ly0][lz1]);
                float4 p010 = up(pmS[lx0][ly1][lz0]), p011 = up(pmS[lx0][ly1][lz1]);
                float4 p100 = up(pmS[lx1][ly0][lz0]), p101 = up(pmS[lx1][ly0][lz1]);
                float4 p110 = up(pmS[lx1][ly1][lz0]), p111 = up(pmS[lx1][ly1][lz1]);
                float w000=(1-wxf)*(1-wyf)*(1-wzf), w001=(1-wxf)*(1-wyf)*wzf;
                float w010=(1-wxf)*wyf*(1-wzf),     w011=(1-wxf)*wyf*wzf;
                float w100=wxf*(1-wyf)*(1-wzf),     w101=wxf*(1-wyf)*wzf;
                float w110=wxf*wyf*(1-wzf),         w111=wxf*wyf*wzf;
                float pw = pweight[(ps0+gx)*96*96 + (ps1+gy)*96 + (ps2+gz)];
                float pr0 = pw*(w000*p000.x + w001*p001.x + w010*p010.x + w011*p011.x + w100*p100.x + w101*p101.x + w110*p110.x + w111*p111.x);
                float pr1 = pw*(w000*p000.y + w001*p001.y + w010*p010.y + w011*p011.y + w100*p100.y + w101*p101.y + w110*p110.y + w111*p111.y);
                float pr2 = pw*(w000*p000.z + w001*p001.z + w010*p010.z + w011*p011.z + w100*p100.z + w101*p101.z + w110*p110.z + w111*p111.z);
                float pr3 = pw*(w000*p000.w + w001*p001.w + w010*p010.w + w011*p011.w + w100*p100.w + w101*p101.w + w110*p110.w + w111*p111.w);

                int gg = g + rz;
                float4 q;
                q.x = unary[gg]      + cw[0]*pr0  + cw[1]*pr1  + cw[2]*pr2  + cw[3]*pr3;
                q.y = unary[gg+N3]   + cw[4]*pr0  + cw[5]*pr1  + cw[6]*pr2  + cw[7]*pr3;
                q.z = unary[gg+2*N3] + cw[8]*pr0  + cw[9]*pr1  + cw[10]*pr2 + cw[11]*pr3;
                q.w = unary[gg+3*N3] + cw[12]*pr0 + cw[13]*pr1 + cw[14]*pr2 + cw[15]*pr3;
                unary4[gg] = q;          // for iterations 2-4
                if (rz == 0) u40 = q; else u41 = q;
            }
        }
        __syncthreads();   // nbS/pmS dead; raw1 reusable as pS
    }

    // ---- halo load: 12^3 = 1728 voxels, 4 rounds of 512 ----
    const float sc = FIRST ? snorm[0] * FSCALE : 0.0f;
    #pragma unroll
    for (int rr = 0; rr < 4; ++rr) {
        int i = tid + rr*512;
        if (i < HX*HY*HZ) {
            int lz = i % HZ; int r = i / HZ;
            int ly = r % HY; int lx = r / HY;
            int hgx = x0b + lx - 2, hgy = y0b + ly - 2, hgz = z0b + lz - 2;
            uint2 pu = make_uint2(0u, 0u);
            unsigned fu = 0u;
            if ((unsigned)hgx < NN && (unsigned)hgy < NN && (unsigned)hgz < NN) {
                int hg = (hgx*NN + hgy)*NN + hgz;
                if (FIRST) {
                    float q0 = unary[hg], q1 = unary[hg+N3], q2 = unary[hg+2*N3], q3 = unary[hg+3*N3];
                    float m = fmaxf(fmaxf(q0,q1), fmaxf(q2,q3));
                    float e0 = fexp2((q0-m)*LOG2E);
                    float e1 = fexp2((q1-m)*LOG2E);
                    float e2 = fexp2((q2-m)*LOG2E);
                    float e3 = fexp2((q3-m)*LOG2E);
                    float inv = 1.0f/(e0+e1+e2+e3);
                    pu = make_uint2(h2u(pkh(e0*inv, e1*inv)), h2u(pkh(e2*inv, e3*inv)));
                    fu = h2u(pkh(img[hg]*sc, img[hg+N3]*sc));
                    if ((unsigned)(lx-2) < 8u && (unsigned)(ly-2) < 8u && (unsigned)(lz-2) < 8u)
                        fpk_out[hg] = fu;   // features for iterations 2-4
                } else {
                    pu = pin[hg];
                    fu = fpk_in[hg];
                }
            }
            pS[lx][ly][lz] = pu;
            fS[lx][ly][lz] = fu;
        }
    }

    // hoisted epilogue operands (s==0 only; FIRST already has them)
    if (!FIRST && s == 0) {
        u40 = unary4[g]; u41 = unary4[g+1];
        sw0 = sweight[0]; sw1 = sweight[1]; sw2 = sweight[2]; sw3 = sweight[3];
        #pragma unroll
        for (int k = 0; k < 16; ++k) cw[k] = compat[k];
    }

    __syncthreads();

    // negated center features (from LDS so the d=0 term is exactly w=1)
    const h2 ncf0 = -u2h(fS[tx+2][ty+2][tz0+2]);
    const h2 ncf1 = -u2h(fS[tx+2][ty+2][tz0+3]);

    h2 a01_0 = (h2)0, a23_0 = (h2)0, a01_1 = (h2)0, a23_1 = (h2)0;

    // wave-uniform split of the 25 (dx,dy) phases across s=0/1:
    // s==1 gets even phases (13), s==0 (epilogue owner) gets odd phases (12).
    #pragma unroll
    for (int pp = 0; pp < 13; ++pp) {
        int p = (1 - s) + 2*pp;
        if (p < 25) {
            int dx = p / 5, dy = p - 5*dx;
            const uint4* pv = reinterpret_cast<const uint4*>(&pS[tx+dx][ty+dy][tz0]);
            const uint2* fv = reinterpret_cast<const uint2*>(&fS[tx+dx][ty+dy][tz0]);
            uint4 qa = pv[0], qb = pv[1], qc = pv[2];   // 6 voxels of packed p
            uint2 fa = fv[0], fb = fv[1], fc = fv[2];   // 6 voxels of packed f

            unsigned fz[6]  = { fa.x, fa.y, fb.x, fb.y, fc.x, fc.y };
            unsigned p01[6] = { qa.x, qa.z, qb.x, qb.z, qc.x, qc.z };
            unsigned p23[6] = { qa.y, qa.w, qb.y, qb.w, qc.y, qc.w };

            #pragma unroll
            for (int dz = 0; dz < 5; ++dz) {
                {
                    h2 d = u2h(fz[dz]) + ncf0;
                    float ww = fexp2(-fdot2(d, d));
                    h2 w2 = pkh(ww, ww);
                    a01_0 = w2 * u2h(p01[dz]) + a01_0;
                    a23_0 = w2 * u2h(p23[dz]) + a23_0;
                }
                {
                    h2 d = u2h(fz[dz+1]) + ncf1;
                    float ww = fexp2(-fdot2(d, d));
                    h2 w2 = pkh(ww, ww);
                    a01_1 = w2 * u2h(p01[dz+1]) + a01_1;
                    a23_1 = w2 * u2h(p23[dz+1]) + a23_1;
                }
            }
        }
    }

    const int pid = (tx*TYD + ty)*TZR + tzg;
    if (s != 0) {
        accS[pid] = make_uint4(h2u(a01_0), h2u(a23_0), h2u(a01_1), h2u(a23_1));
    }
    __syncthreads();

    if (s == 0) {
        {
            uint4 v = accS[pid];
            a01_0 += u2h(v.x); a23_0 += u2h(v.y);
            a01_1 += u2h(v.z); a23_1 += u2h(v.w);
        }

        float p0, p1, p2, p3;
        float r00, r10, r20, r30, r01, r11, r21, r31;
        p0 = sw0*(float)a01_0.x; p1 = sw1*(float)a01_0.y;
        p2 = sw2*(float)a23_0.x; p3 = sw3*(float)a23_0.y;
        r00 = u40.x + cw[0]*p0  + cw[1]*p1  + cw[2]*p2  + cw[3]*p3;
        r10 = u40.y + cw[4]*p0  + cw[5]*p1  + cw[6]*p2  + cw[7]*p3;
        r20 = u40.z + cw[8]*p0  + cw[9]*p1  + cw[10]*p2 + cw[11]*p3;
        r30 = u40.w + cw[12]*p0 + cw[13]*p1 + cw[14]*p2 + cw[15]*p3;
        p0 = sw0*(float)a01_1.x; p1 = sw1*(float)a01_1.y;
        p2 = sw2*(float)a23_1.x; p3 = sw3*(float)a23_1.y;
        r01 = u41.x + cw[0]*p0  + cw[1]*p1  + cw[2]*p2  + cw[3]*p3;
        r11 = u41.y + cw[4]*p0  + cw[5]*p1  + cw[6]*p2  + cw[7]*p3;
        r21 = u41.z + cw[8]*p0  + cw[9]*p1  + cw[10]*p2 + cw[11]*p3;
        r31 = u41.w + cw[12]*p0 + cw[13]*p1 + cw[14]*p2 + cw[15]*p3;

        if (LAST) {
            *(float2*)(qout + 0*N3 + g) = make_float2(r00, r01);
            *(float2*)(qout + 1*N3 + g) = make_float2(r10, r11);
            *(float2*)(qout + 2*N3 + g) = make_float2(r20, r21);
            *(float2*)(qout + 3*N3 + g) = make_float2(r30, r31);
        } else {
            // softmax + pack (producer side of next iteration)
            float m0 = fmaxf(fmaxf(r00,r10), fmaxf(r20,r30));
            float e00 = fexp2((r00-m0)*LOG2E), e10 = fexp2((r10-m0)*LOG2E);
            float e20 = fexp2((r20-m0)*LOG2E), e30 = fexp2((r30-m0)*LOG2E);
            float i0 = 1.0f/(e00+e10+e20+e30);
            float m1 = fmaxf(fmaxf(r01,r11), fmaxf(r21,r31));
            float e01 = fexp2((r01-m1)*LOG2E), e11 = fexp2((r11-m1)*LOG2E);
            float e21 = fexp2((r21-m1)*LOG2E), e31 = fexp2((r31-m1)*LOG2E);
            float i1 = 1.0f/(e01+e11+e21+e31);
            uint4 o = make_uint4(h2u(pkh(e00*i0, e10*i0)), h2u(pkh(e20*i0, e30*i0)),
                                 h2u(pkh(e01*i1, e11*i1)), h2u(pkh(e21*i1, e31*i1)));
            *reinterpret_cast<uint4*>(&pout[g]) = o;   // g even -> 16B aligned
        }
    }
}

// ---------------- launcher ----------------

extern "C" void kernel_launch(void* const* d_in, const int* in_sizes, int n_in,
                              void* d_out, int out_size, void* d_ws, size_t ws_size,
                              hipStream_t stream)
{
    const float* unary   = (const float*)d_in[0];
    const float* img     = (const float*)d_in[1];
    const float* atlas   = (const float*)d_in[2];
    const float* alabel  = (const float*)d_in[3];
    const int*   pstart  = (const int*)d_in[4];
    const float* snorm   = (const float*)d_in[5];
    const float* sweight = (const float*)d_in[6];
    const float* pnorm   = (const float*)d_in[7];
    const float* pweight = (const float*)d_in[8];
    const float* compat  = (const float*)d_in[9];
    float* out = (float*)d_out;
    float* ws  = (float*)d_ws;

    float4*   unary4 = (float4*)ws;               // N3 float4 (4 MB)
    uint2*    pA     = (uint2*)(ws + 4*N3);       // N3 uint2  (2 MB)
    uint2*    pB     = (uint2*)(ws + 6*N3);       // N3 uint2  (2 MB)
    unsigned* fpk    = (unsigned*)(ws + 8*N3);    // N3 uint   (1 MB)

    dim3 grid(512), block(TZR, TYD, 16);
    k_iter<true, false><<<grid, block, 0, stream>>>(unary, pA, fpk, img, atlas, alabel,
        pnorm, snorm, pweight, pstart, sweight, compat, unary4, fpk, pA, out);
    k_iter<false,false><<<grid, block, 0, stream>>>(unary, pA, fpk, img, atlas, alabel,
        pnorm, snorm, pweight, pstart, sweight, compat, unary4, fpk, pB, out);
    k_iter<false,false><<<grid, block, 0, stream>>>(unary, pB, fpk, img, atlas, alabel,
        pnorm, snorm, pweight, pstart, sweight, compat, unary4, fpk, pA, out);
    k_iter<false,true ><<<grid, block, 0, stream>>>(unary, pA, fpk, img, atlas, alabel,
        pnorm, snorm, pweight, pstart, sweight, compat, unary4, fpk, pB, out);
}

// Round 15
// 88.109 us; speedup vs baseline: 1.0434x; 1.0322x over previous
//
#include <hip/hip_runtime.h>

#define NN 64
#define N3 (64*64*64)
#define DS 32

#define LOG2E 1.4426950408889634f
// sqrt(0.5 * log2(e)) — features pre-scaled so w = exp2(-dot2(d,d))
#define FSCALE 0.8493218002880191f

typedef _Float16 h2  __attribute__((ext_vector_type(2)));
typedef __fp16   h2f __attribute__((ext_vector_type(2)));

__device__ __forceinline__ float fexp2(float x) { return __builtin_amdgcn_exp2f(x); }

__device__ __forceinline__ h2 u2h(unsigned u) { union { unsigned u; h2 h; } c; c.u = u; return c.h; }
__device__ __forceinline__ unsigned h2u(h2 h) { union { unsigned u; h2 h; } c; c.h = h; return c.u; }
__device__ __forceinline__ h2 pkh(float a, float b) {
    union { h2f a; h2 b; } c; c.a = __builtin_amdgcn_cvt_pkrtz(a, b); return c.b;
}
__device__ __forceinline__ float fdot2(h2 a, h2 b) {
    union { h2 h; h2f f; } ca, cb; ca.h = a; cb.h = b;
    return __builtin_amdgcn_fdot2(ca.f, cb.f, 0.0f, false);
}

// ---------------- fused mean-field iteration (R12 = best measured) ----------------
// Tile 8^3, 1024 threads (tzg=4, ty=8, (tx,s)=32), RZ=2, S=4 wave-uniform
// phase split. 512 blocks, 2 blocks/CU, 8 waves/SIMD. XCD-chunked block
// swizzle for inter-launch L2 locality. FIRST computes the prior path
// block-locally and folds it into unary4; p flows between iterations as
// producer-packed f16x4.

#define TXD 8
#define TYD 8
#define TZD 8
#define TZR 4
#define RZ 2
#define HX 12
#define HY 12
#define HZ 12
#define PZ 14          // pS padded z stride
#define CPX 6          // coarse pm extent per block
#define CSX 10         // staged coarse extent (pm + halo 2)

template<bool FIRST, bool LAST>
__global__ __launch_bounds__(1024, 8) void k_iter(
    const float* __restrict__ unary,     // planar [4][N3]
    const uint2* __restrict__ pin,       // !FIRST: packed f16x4 softmax
    const unsigned* __restrict__ fpk_in, // !FIRST: packed img features
    const float* __restrict__ img,
    const float* __restrict__ atlas,
    const float* __restrict__ alabel,
    const float* __restrict__ pnorm,
    const float* __restrict__ snorm,
    const float* __restrict__ pweight,
    const int* __restrict__ pstart,
    const float* __restrict__ sweight,
    const float* __restrict__ compat,
    float4* __restrict__ unary4,         // FIRST: write; !FIRST: read
    unsigned* __restrict__ fpk_out,      // FIRST: write
    uint2* __restrict__ pout,            // !LAST: packed softmax out
    float* __restrict__ qout)            // LAST: planar q out
{
    // raw1 is phase-unioned: nbS (prior staging, FIRST only) then pS (main).
    __shared__ __align__(16) unsigned char raw1[16384];
    auto nbS = reinterpret_cast<uint4 (*)[CSX][CSX]>(raw1);   // [10][10][10] {f2pk,l01,l23,f1pk}
    auto pS  = reinterpret_cast<uint2 (*)[HY][PZ]>(raw1);     // [12][12][14] p f16x4
    __shared__ __align__(8)  unsigned fS[HX][HY][PZ];         // features f16x2
    __shared__ __align__(16) uint4    accS[3][TXD*TYD*TZR];   // partial sums
    __shared__ __align__(8)  uint2    pmS[CPX][CPX][CPX];     // prior message f16x4

    const int tzg = threadIdx.x, ty = threadIdx.y;
    const int tx = threadIdx.z & 7, s = threadIdx.z >> 3;     // s wave-uniform

    // XCD-chunked swizzle: dispatch index d -> XCD d%8 (HW round-robin).
    const int bid = blockIdx.x;
    const int w   = ((bid & 7) << 6) | (bid >> 3);
    const int x0b = (w >> 6) * TXD;
    const int y0b = ((w >> 3) & 7) * TYD;
    const int z0b = (w & 7) * TZD;

    const int tid = threadIdx.x + TZR*threadIdx.y + (TZR*TYD)*threadIdx.z;

    const int tz0 = tzg * RZ;
    const int gx = x0b + tx, gy = y0b + ty;
    const int g = (gx*NN + gy)*NN + z0b + tz0;

    float4 u40, u41;
    float sw0, sw1, sw2, sw3;
    float cw[16];

    if (FIRST) {
        const int cxlo = (x0b*31)/63, cylo = (y0b*31)/63, czlo = (z0b*31)/63;
        const float pnf = pnorm[0] * FSCALE;

        // ---- phase 1: stage coarse features/labels (10^3) ----
        if (tid < CSX*CSX*CSX) {
            int lz = tid % CSX; int r = tid / CSX; int ly = r % CSX; int lx = r / CSX;
            int cx = cxlo - 2 + lx, cy = cylo - 2 + ly, cz = czlo - 2 + lz;
            uint4 v = make_uint4(0u, 0u, 0u, 0u);
            if ((unsigned)cx < DS && (unsigned)cy < DS && (unsigned)cz < DS) {
                const float scale = 63.0f / 31.0f;
                float posx = cx*scale; int a0i = (int)posx; float wx = posx - a0i; int a1i = a0i+1 <= 63 ? a0i+1 : 63;
                float posy = cy*scale; int b0i = (int)posy; float wy = posy - b0i; int b1i = b0i+1 <= 63 ? b0i+1 : 63;
                float posz = cz*scale; int d0i = (int)posz; float wz = posz - d0i; int d1i = d0i+1 <= 63 ? d0i+1 : 63;
                float w000=(1-wx)*(1-wy)*(1-wz), w001=(1-wx)*(1-wy)*wz;
                float w010=(1-wx)*wy*(1-wz),     w011=(1-wx)*wy*wz;
                float w100=wx*(1-wy)*(1-wz),     w101=wx*(1-wy)*wz;
                float w110=wx*wy*(1-wz),         w111=wx*wy*wz;
                int c000=(a0i*NN+b0i)*NN+d0i, c001=(a0i*NN+b0i)*NN+d1i;
                int c010=(a0i*NN+b1i)*NN+d0i, c011=(a0i*NN+b1i)*NN+d1i;
                int c100=(a1i*NN+b0i)*NN+d0i, c101=(a1i*NN+b0i)*NN+d1i;
                int c110=(a1i*NN+b1i)*NN+d0i, c111=(a1i*NN+b1i)*NN+d1i;
                auto tri = [&](const float* p) -> float {
                    return p[c000]*w000 + p[c001]*w001 + p[c010]*w010 + p[c011]*w011
                         + p[c100]*w100 + p[c101]*w101 + p[c110]*w110 + p[c111]*w111;
                };
                const float4* lab = (const float4*)alabel;
                float4 l = make_float4(0.f,0.f,0.f,0.f);
                {
                    float4 t;
                    t = lab[c000]; l.x += w000*t.x; l.y += w000*t.y; l.z += w000*t.z; l.w += w000*t.w;
                    t = lab[c001]; l.x += w001*t.x; l.y += w001*t.y; l.z += w001*t.z; l.w += w001*t.w;
                    t = lab[c010]; l.x += w010*t.x; l.y += w010*t.y; l.z += w010*t.z; l.w += w010*t.w;
                    t = lab[c011]; l.x += w011*t.x; l.y += w011*t.y; l.z += w011*t.z; l.w += w011*t.w;
                    t = lab[c100]; l.x += w100*t.x; l.y += w100*t.y; l.z += w100*t.z; l.w += w100*t.w;
                    t = lab[c101]; l.x += w101*t.x; l.y += w101*t.y; l.z += w101*t.z; l.w += w101*t.w;
                    t = lab[c110]; l.x += w110*t.x; l.y += w110*t.y; l.z += w110*t.z; l.w += w110*t.w;
                    t = lab[c111]; l.x += w111*t.x; l.y += w111*t.y; l.z += w111*t.z; l.w += w111*t.w;
                }
                v = make_uint4(h2u(pkh(pnf*tri(atlas), pnf*tri(atlas + N3))),
                               h2u(pkh(l.x, l.y)), h2u(pkh(l.z, l.w)),
                               h2u(pkh(pnf*tri(img), pnf*tri(img + N3))));
            }
            nbS[lx][ly][lz] = v;
        }
        __syncthreads();

        // ---- phase 2: prior message on the 6^3 coarse points ----
        if (tid < CPX*CPX*CPX) {
            int pz = tid % CPX; int r = tid / CPX; int py = r % CPX; int px = r / CPX;
            int cx = cxlo + px, cy = cylo + py, cz = czlo + pz;
            uint2 o = make_uint2(0u, 0u);
            if (cx < DS && cy < DS && cz < DS) {
                h2 ncf = -u2h(nbS[px+2][py+2][pz+2].w);
                float a0=0.f, a1=0.f, a2=0.f, a3=0.f;
                for (int dx = -2; dx <= 2; ++dx) {
                    int xx = cx + dx; if ((unsigned)xx >= DS) continue;
                    for (int dy = -2; dy <= 2; ++dy) {
                        int yy = cy + dy; if ((unsigned)yy >= DS) continue;
                        #pragma unroll
                        for (int dz = -2; dz <= 2; ++dz) {
                            int zz = cz + dz; if ((unsigned)zz >= DS) continue;
                            uint4 v = nbS[px+2+dx][py+2+dy][pz+2+dz];
                            h2 d = u2h(v.x) + ncf;
                            float ww = fexp2(-fdot2(d, d));
                            h2 l01 = u2h(v.y), l23 = u2h(v.z);
                            a0 += ww*(float)l01.x; a1 += ww*(float)l01.y;
                            a2 += ww*(float)l23.x; a3 += ww*(float)l23.y;
                        }
                    }
                }
                o = make_uint2(h2u(pkh(a0, a1)), h2u(pkh(a2, a3)));
            }
            pmS[px][py][pz] = o;
        }
        __syncthreads();

        // ---- phase 3: s==0 threads upsample + fold their own 2 voxels ----
        if (s == 0) {
            sw0 = sweight[0]; sw1 = sweight[1]; sw2 = sweight[2]; sw3 = sweight[3];
            #pragma unroll
            for (int k = 0; k < 16; ++k) cw[k] = compat[k];

            const float S13 = 31.0f / 63.0f;
            float posx = gx*S13; int xc0 = (int)posx; float wxf = posx - xc0; int xc1 = xc0 < 31 ? xc0+1 : 31;
            float posy = gy*S13; int yc0 = (int)posy; float wyf = posy - yc0; int yc1 = yc0 < 31 ? yc0+1 : 31;
            int lx0 = xc0-cxlo, lx1 = xc1-cxlo;
            int ly0 = yc0-cylo, ly1 = yc1-cylo;
            const int ps0 = pstart[0], ps1 = pstart[1], ps2 = pstart[2];

            auto up = [&](uint2 u) -> float4 {
                h2 a = u2h(u.x), b = u2h(u.y);
                return make_float4((float)a.x, (float)a.y, (float)b.x, (float)b.y);
            };

            #pragma unroll
            for (int rz = 0; rz < RZ; ++rz) {
                int gz = z0b + tz0 + rz;
                float posz = gz*S13; int zc0 = (int)posz; float wzf = posz - zc0; int zc1 = zc0 < 31 ? zc0+1 : 31;
                int lz0 = zc0-czlo, lz1 = zc1-czlo;
                float4 p000 = up(pmS[lx0][ly0][lz0]), p001 = up(pmS[lx0][ly0][lz1]);
                float4 p010 = up(pmS[lx0][ly1][lz0]), p011 = up(pmS[lx0][ly1][lz1]);
                float4 p100 = up(pmS[lx1][ly0][lz0]), p101 = up(pmS[lx1][ly0][lz1]);
                float4 p110 = up(pmS[lx1][ly1][lz0]), p111 = up(pmS[lx1][ly1][lz1]);
                float w000=(1-wxf)*(1-wyf)*(1-wzf), w001=(1-wxf)*(1-wyf)*wzf;
                float w010=(1-wxf)*wyf*(1-wzf),     w011=(1-wxf)*wyf*wzf;
                float w100=wxf*(1-wyf)*(1-wzf),     w101=wxf*(1-wyf)*wzf;
                float w110=wxf*wyf*(1-wzf),         w111=wxf*wyf*wzf;
                float pw = pweight[(ps0+gx)*96*96 + (ps1+gy)*96 + (ps2+gz)];
                float pr0 = pw*(w000*p000.x + w001*p001.x + w010*p010.x + w011*p011.x + w100*p100.x + w101*p101.x + w110*p110.x + w111*p111.x);
                float pr1 = pw*(w000*p000.y + w001*p001.y + w010*p010.y + w011*p011.y + w100*p100.y + w101*p101.y + w110*p110.y + w111*p111.y);
                float pr2 = pw*(w000*p000.z + w001*p001.z + w010*p010.z + w011*p011.z + w100*p100.z + w101*p101.z + w110*p110.z + w111*p111.z);
                float pr3 = pw*(w000*p000.w + w001*p001.w + w010*p010.w + w011*p011.w + w100*p100.w + w101*p101.w + w110*p110.w + w111*p111.w);

                int gg = g + rz;
                float4 q;
                q.x = unary[gg]      + cw[0]*pr0  + cw[1]*pr1  + cw[2]*pr2  + cw[3]*pr3;
                q.y = unary[gg+N3]   + cw[4]*pr0  + cw[5]*pr1  + cw[6]*pr2  + cw[7]*pr3;
                q.z = unary[gg+2*N3] + cw[8]*pr0  + cw[9]*pr1  + cw[10]*pr2 + cw[11]*pr3;
                q.w = unary[gg+3*N3] + cw[12]*pr0 + cw[13]*pr1 + cw[14]*pr2 + cw[15]*pr3;
                unary4[gg] = q;          // for iterations 2-4
                if (rz == 0) u40 = q; else u41 = q;
            }
        }
        __syncthreads();   // nbS/pmS dead; raw1 reusable as pS
    }

    // ---- halo load: 12^3 = 1728 voxels, 2 rounds of 1024 ----
    const float sc = FIRST ? snorm[0] * FSCALE : 0.0f;
    #pragma unroll
    for (int rr = 0; rr < 2; ++rr) {
        int i = tid + rr*1024;
        if (i < HX*HY*HZ) {
            int lz = i % HZ; int r = i / HZ;
            int ly = r % HY; int lx = r / HY;
            int hgx = x0b + lx - 2, hgy = y0b + ly - 2, hgz = z0b + lz - 2;
            uint2 pu = make_uint2(0u, 0u);
            unsigned fu = 0u;
            if ((unsigned)hgx < NN && (unsigned)hgy < NN && (unsigned)hgz < NN) {
                int hg = (hgx*NN + hgy)*NN + hgz;
                if (FIRST) {
                    float q0 = unary[hg], q1 = unary[hg+N3], q2 = unary[hg+2*N3], q3 = unary[hg+3*N3];
                    float m = fmaxf(fmaxf(q0,q1), fmaxf(q2,q3));
                    float e0 = fexp2((q0-m)*LOG2E);
                    float e1 = fexp2((q1-m)*LOG2E);
                    float e2 = fexp2((q2-m)*LOG2E);
                    float e3 = fexp2((q3-m)*LOG2E);
                    float inv = 1.0f/(e0+e1+e2+e3);
                    pu = make_uint2(h2u(pkh(e0*inv, e1*inv)), h2u(pkh(e2*inv, e3*inv)));
                    fu = h2u(pkh(img[hg]*sc, img[hg+N3]*sc));
                    if ((unsigned)(lx-2) < 8u && (unsigned)(ly-2) < 8u && (unsigned)(lz-2) < 8u)
                        fpk_out[hg] = fu;   // features for iterations 2-4
                } else {
                    pu = pin[hg];
                    fu = fpk_in[hg];
                }
            }
            pS[lx][ly][lz] = pu;
            fS[lx][ly][lz] = fu;
        }
    }

    // hoisted epilogue operands (s==0 only; FIRST already has them)
    if (!FIRST && s == 0) {
        u40 = unary4[g]; u41 = unary4[g+1];
        sw0 = sweight[0]; sw1 = sweight[1]; sw2 = sweight[2]; sw3 = sweight[3];
        #pragma unroll
        for (int k = 0; k < 16; ++k) cw[k] = compat[k];
    }

    __syncthreads();

    // negated center features (from LDS so the d=0 term is exactly w=1)
    const h2 ncf0 = -u2h(fS[tx+2][ty+2][tz0+2]);
    const h2 ncf1 = -u2h(fS[tx+2][ty+2][tz0+3]);

    h2 a01_0 = (h2)0, a23_0 = (h2)0, a01_1 = (h2)0, a23_1 = (h2)0;

    // wave-uniform split of the 25 (dx,dy) phases across s=0..3 (s==3: 7,
    // s==0 = epilogue owner: 6).
    #pragma unroll
    for (int pp = 0; pp < 7; ++pp) {
        int p = (3 - s) + 4*pp;
        if (p < 25) {
            int dx = p / 5, dy = p - 5*dx;
            const uint4* pv = reinterpret_cast<const uint4*>(&pS[tx+dx][ty+dy][tz0]);
            const uint2* fv = reinterpret_cast<const uint2*>(&fS[tx+dx][ty+dy][tz0]);
            uint4 qa = pv[0], qb = pv[1], qc = pv[2];   // 6 voxels of packed p
            uint2 fa = fv[0], fb = fv[1], fc = fv[2];   // 6 voxels of packed f

            unsigned fz[6]  = { fa.x, fa.y, fb.x, fb.y, fc.x, fc.y };
            unsigned p01[6] = { qa.x, qa.z, qb.x, qb.z, qc.x, qc.z };
            unsigned p23[6] = { qa.y, qa.w, qb.y, qb.w, qc.y, qc.w };

            #pragma unroll
            for (int dz = 0; dz < 5; ++dz) {
                {
                    h2 d = u2h(fz[dz]) + ncf0;
                    float ww = fexp2(-fdot2(d, d));
                    h2 w2 = pkh(ww, ww);
                    a01_0 = w2 * u2h(p01[dz]) + a01_0;
                    a23_0 = w2 * u2h(p23[dz]) + a23_0;
                }
                {
                    h2 d = u2h(fz[dz+1]) + ncf1;
                    float ww = fexp2(-fdot2(d, d));
                    h2 w2 = pkh(ww, ww);
                    a01_1 = w2 * u2h(p01[dz+1]) + a01_1;
                    a23_1 = w2 * u2h(p23[dz+1]) + a23_1;
                }
            }
        }
    }

    const int pid = (tx*TYD + ty)*TZR + tzg;
    if (s != 0) {
        accS[s-1][pid] = make_uint4(h2u(a01_0), h2u(a23_0), h2u(a01_1), h2u(a23_1));
    }
    __syncthreads();

    if (s == 0) {
        #pragma unroll
        for (int j = 0; j < 3; ++j) {
            uint4 v = accS[j][pid];
            a01_0 += u2h(v.x); a23_0 += u2h(v.y);
            a01_1 += u2h(v.z); a23_1 += u2h(v.w);
        }

        float p0, p1, p2, p3;
        float r00, r10, r20, r30, r01, r11, r21, r31;
        p0 = sw0*(float)a01_0.x; p1 = sw1*(float)a01_0.y;
        p2 = sw2*(float)a23_0.x; p3 = sw3*(float)a23_0.y;
        r00 = u40.x + cw[0]*p0  + cw[1]*p1  + cw[2]*p2  + cw[3]*p3;
        r10 = u40.y + cw[4]*p0  + cw[5]*p1  + cw[6]*p2  + cw[7]*p3;
        r20 = u40.z + cw[8]*p0  + cw[9]*p1  + cw[10]*p2 + cw[11]*p3;
        r30 = u40.w + cw[12]*p0 + cw[13]*p1 + cw[14]*p2 + cw[15]*p3;
        p0 = sw0*(float)a01_1.x; p1 = sw1*(float)a01_1.y;
        p2 = sw2*(float)a23_1.x; p3 = sw3*(float)a23_1.y;
        r01 = u41.x + cw[0]*p0  + cw[1]*p1  + cw[2]*p2  + cw[3]*p3;
        r11 = u41.y + cw[4]*p0  + cw[5]*p1  + cw[6]*p2  + cw[7]*p3;
        r21 = u41.z + cw[8]*p0  + cw[9]*p1  + cw[10]*p2 + cw[11]*p3;
        r31 = u41.w + cw[12]*p0 + cw[13]*p1 + cw[14]*p2 + cw[15]*p3;

        if (LAST) {
            *(float2*)(qout + 0*N3 + g) = make_float2(r00, r01);
            *(float2*)(qout + 1*N3 + g) = make_float2(r10, r11);
            *(float2*)(qout + 2*N3 + g) = make_float2(r20, r21);
            *(float2*)(qout + 3*N3 + g) = make_float2(r30, r31);
        } else {
            // softmax + pack (producer side of next iteration)
            float m0 = fmaxf(fmaxf(r00,r10), fmaxf(r20,r30));
            float e00 = fexp2((r00-m0)*LOG2E), e10 = fexp2((r10-m0)*LOG2E);
            float e20 = fexp2((r20-m0)*LOG2E), e30 = fexp2((r30-m0)*LOG2E);
            float i0 = 1.0f/(e00+e10+e20+e30);
            float m1 = fmaxf(fmaxf(r01,r11), fmaxf(r21,r31));
            float e01 = fexp2((r01-m1)*LOG2E), e11 = fexp2((r11-m1)*LOG2E);
            float e21 = fexp2((r21-m1)*LOG2E), e31 = fexp2((r31-m1)*LOG2E);
            float i1 = 1.0f/(e01+e11+e21+e31);
            uint4 o = make_uint4(h2u(pkh(e00*i0, e10*i0)), h2u(pkh(e20*i0, e30*i0)),
                                 h2u(pkh(e01*i1, e11*i1)), h2u(pkh(e21*i1, e31*i1)));
            *reinterpret_cast<uint4*>(&pout[g]) = o;   // g even -> 16B aligned
        }
    }
}

// ---------------- launcher ----------------

extern "C" void kernel_launch(void* const* d_in, const int* in_sizes, int n_in,
                              void* d_out, int out_size, void* d_ws, size_t ws_size,
                              hipStream_t stream)
{
    const float* unary   = (const float*)d_in[0];
    const float* img     = (const float*)d_in[1];
    const float* atlas   = (const float*)d_in[2];
    const float* alabel  = (const float*)d_in[3];
    const int*   pstart  = (const int*)d_in[4];
    const float* snorm   = (const float*)d_in[5];
    const float* sweight = (const float*)d_in[6];
    const float* pnorm   = (const float*)d_in[7];
    const float* pweight = (const float*)d_in[8];
    const float* compat  = (const float*)d_in[9];
    float* out = (float*)d_out;
    float* ws  = (float*)d_ws;

    float4*   unary4 = (float4*)ws;               // N3 float4 (4 MB)
    uint2*    pA     = (uint2*)(ws + 4*N3);       // N3 uint2  (2 MB)
    uint2*    pB     = (uint2*)(ws + 6*N3);       // N3 uint2  (2 MB)
    unsigned* fpk    = (unsigned*)(ws + 8*N3);    // N3 uint   (1 MB)

    dim3 grid(512), block(TZR, TYD, 32);
    k_iter<true, false><<<grid, block, 0, stream>>>(unary, pA, fpk, img, atlas, alabel,
        pnorm, snorm, pweight, pstart, sweight, compat, unary4, fpk, pA, out);
    k_iter<false,false><<<grid, block, 0, stream>>>(unary, pA, fpk, img, atlas, alabel,
        pnorm, snorm, pweight, pstart, sweight, compat, unary4, fpk, pB, out);
    k_iter<false,false><<<grid, block, 0, stream>>>(unary, pB, fpk, img, atlas, alabel,
        pnorm, snorm, pweight, pstart, sweight, compat, unary4, fpk, pA, out);
    k_iter<false,true ><<<grid, block, 0, stream>>>(unary, pA, fpk, img, atlas, alabel,
        pnorm, snorm, pweight, pstart, sweight, compat, unary4, fpk, pB, out);
}